// Round 11
// baseline (237.608 us; speedup 1.0000x reference)
//
#include <hip/hip_runtime.h>
#include <math.h>

#define Bn 4
#define Cn 256
#define Hn 64
#define Wn 64
#define On 256
#define HWn 4096
#define Pn 16384   // B*H*W
#define Kc 2304    // 9*256

// s_waitcnt imm: vmcnt=63 (no wait), expcnt=7 (no wait), lgkmcnt=0 (drain LDS)
#define LGKM0 0xc07f

typedef _Float16 half8 __attribute__((ext_vector_type(8)));
typedef float floatx4 __attribute__((ext_vector_type(4)));

// ---------------------------------------------------------------------------
// ONE init kernel: blocks 0..4095 = fp32 NCHW -> f16 NHWC transpose;
// 4096..4863 = main-weight pack; 4864..4959 = offset-weight pack.
__global__ void k_init(const float* __restrict__ x, _Float16* __restrict__ act0,
                       const float* __restrict__ w0, const float* __restrict__ w1,
                       const float* __restrict__ w2, const float* __restrict__ wo0,
                       const float* __restrict__ wo1, const float* __restrict__ wo2,
                       _Float16* __restrict__ wtp, _Float16* __restrict__ wbop) {
  int bx = blockIdx.x;
  int tid = threadIdx.x;
  if (bx < 4096) {
    __shared__ float tile[32][33];
    int cx = bx & 127, cy = (bx >> 7) & 7, b = bx >> 10;
    int c0 = cx * 32, r0 = cy * 32;
    int tx = tid & 31, ty = tid >> 5;
    const float* ib = x + (size_t)b * Cn * HWn;
    _Float16* ob = act0 + (size_t)b * Cn * HWn;
#pragma unroll
    for (int i = 0; i < 32; i += 8)
      tile[ty + i][tx] = ib[(size_t)(r0 + ty + i) * HWn + (c0 + tx)];
    __syncthreads();
#pragma unroll
    for (int i = 0; i < 32; i += 8)
      ob[(size_t)(c0 + ty + i) * Cn + (r0 + tx)] = (_Float16)tile[tx][ty + i];
  } else if (bx < 4864) {
    int b2 = bx - 4096;
    int l = b2 >> 8;
    int n = b2 & 255;
    const float* w = (l == 0) ? w0 : (l == 1) ? w1 : w2;
    _Float16* dst = wtp + (size_t)l * 256 * Kc;
    int g = n >> 4, col = n & 15;
    int cq = tid >> 6;
    int kk = tid & 63;
    int kq = kk >> 5;
    int k32 = kk & 31;
    int quad = k32 >> 3;
    int e = k32 & 7;
    const float* src = w + (size_t)n * 2304 + (size_t)tid * 9;
#pragma unroll
    for (int t = 0; t < 9; ++t) {
      int c = t * 4 + cq;
      size_t d = ((size_t)((c * 16 + g) * 2 + kq)) * 512 + (quad * 16 + col) * 8 + e;
      dst[d] = (_Float16)src[t];
    }
  } else {
    int b3 = bx - 4864;
    int l = b3 >> 5;
    int n = b3 & 31;
    const float* w = (l == 0) ? wo0 : (l == 1) ? wo1 : wo2;
    _Float16* dst = wbop + (size_t)l * 36 * 2048;
    int g = n >> 4, col = n & 15;
    int cw = tid >> 6;
    int r = tid & 63;
    int kq = r >> 5;
    int r2 = r & 31;
    int quad = r2 >> 3;
    int e = r2 & 7;
#pragma unroll
    for (int t = 0; t < 9; ++t) {
      int c = t * 4 + cw;
      size_t d = ((size_t)((c * 2 + g) * 2 + kq)) * 512 + (quad * 16 + col) * 8 + e;
      dst[d] = (n < 27) ? (_Float16)w[((size_t)n * 256 + tid) * 9 + t] : (_Float16)0.f;
    }
  }
}

// ---------------------------------------------------------------------------
// FUSED layer kernel — depth-2 prefetch: two register sets ping-pong so chunk
// c+1's loads are issued BEFORE chunk c's stage-write consumes set[c&1]; the
// in-flight window is a full loop body (write+barrier+ds_reads+MFMA).
__global__ __launch_bounds__(512) void k_layer(
    const _Float16* __restrict__ xh,
    const _Float16* __restrict__ wbop, const float* __restrict__ boff,
    const _Float16* __restrict__ wtp, const float* __restrict__ bias,
    _Float16* __restrict__ outh, float* __restrict__ outf) {
  __shared__ __align__(16) _Float16 As[2][64][72];    // 18.4 KB
  __shared__ __align__(16) _Float16 Bs[2][16384];     // 64 KB
  __shared__ __align__(16) float sampS[64][9][8];     // 18 KB

  int p0 = blockIdx.x * 64;
  int tid = threadIdx.x;       // 0..511
  int lane = tid & 63;
  int wave = tid >> 6;         // 0..7
  int quad = lane >> 4;
  int col = lane & 15;

  int ar = tid >> 3;           // staging/gather row 0..63
  int aci = (tid & 7) * 8;     // 8-channel segment

  int p = p0 + ar;
  int bimg = p >> 12;
  int yx = p & 4095;
  int y = yx >> 6, x = yx & 63;

  half8 zero8;
#pragma unroll
  for (int e = 0; e < 8; ++e) zero8[e] = (_Float16)0.f;

  // ================= phase 1: offset conv =================
  _Float16* Bo0 = &Bs[0][0];
  _Float16* Bo1 = &Bs[0][2048];
  float* omS = (float*)&Bs[1][0];   // [64][33]

  int mi = wave >> 1;   // 0..3 (16-row group)
  int ng = wave & 1;    // 0..1 (16-col group)

  floatx4 acc1 = (floatx4){0.f, 0.f, 0.f, 0.f};
  half8 ga1[2], gb1[2];
  ga1[0] = zero8; ga1[1] = zero8; gb1[0] = zero8; gb1[1] = zero8;
  int abase = 0;
  bool avalid = false;
  {
    int sy = y - 1, sx = x - 1;
    avalid = (sy >= 0) & (sy < Hn) & (sx >= 0) & (sx < Wn);
    abase = (((bimg * Hn + (avalid ? sy : 0)) * Wn) + (avalid ? sx : 0)) * Cn;
    if (avalid) ga1[0] = *(const half8*)(xh + (size_t)abase + aci);
    if (tid < 256) gb1[0] = *(const half8*)(wbop + (size_t)tid * 8);
  }

#pragma unroll
  for (int c = 0; c < 36; ++c) {
    int buf = c & 1;
    // issue chunk c+1 loads FIRST into the other register set
    if (c < 35) {
      int cn = c + 1;
      int tn = cn >> 2;
      int cin = (cn & 3) * 64;
      if ((cn & 3) == 0) {
        int sy = y + tn / 3 - 1;
        int sx = x + tn % 3 - 1;
        avalid = (sy >= 0) & (sy < Hn) & (sx >= 0) & (sx < Wn);
        abase = (((bimg * Hn + (avalid ? sy : 0)) * Wn) + (avalid ? sx : 0)) * Cn;
      }
      ga1[!buf] = zero8;
      if (avalid) ga1[!buf] = *(const half8*)(xh + (size_t)abase + cin + aci);
      if (tid < 256) gb1[!buf] = *(const half8*)(wbop + (size_t)cn * 2048 + tid * 8);
    }

    // stage chunk c (vmcnt waits set[buf] only — set[!buf] stays in flight)
    *(half8*)&As[buf][ar][aci] = ga1[buf];
    if (tid < 256) *(half8*)&(buf ? Bo1 : Bo0)[tid * 8] = gb1[buf];

    __builtin_amdgcn_s_waitcnt(LGKM0);   // LDS visible; vmem NOT drained
    __builtin_amdgcn_s_barrier();

    const _Float16* BoB = buf ? Bo1 : Bo0;
#pragma unroll
    for (int kq = 0; kq < 2; ++kq) {
      half8 af = *(const half8*)&As[buf][mi * 16 + col][kq * 32 + quad * 8];
      half8 bf = *(const half8*)&BoB[(ng * 2 + kq) * 512 + lane * 8];
      acc1 = __builtin_amdgcn_mfma_f32_16x16x32_f16(af, bf, acc1, 0, 0, 0);
    }
  }

  // om -> LDS
  {
    int n1 = ng * 16 + col;
    if (n1 < 27) {
      float bb = boff[n1];
#pragma unroll
      for (int r = 0; r < 4; ++r)
        omS[(mi * 16 + quad * 4 + r) * 33 + n1] = acc1[r] + bb;
    }
  }
  __syncthreads();

  // fused coords: 64 px x 9 taps = 576 entries -> sampS (LDS)
  for (int e = tid; e < 576; e += 512) {
    int lp = e / 9;
    int k = e - lp * 9;
    int pp = p0 + lp;
    int bi = pp >> 12;
    int pyx = pp & 4095;
    int py = pyx >> 6, px = pyx & 63;

    float dy = omS[lp * 33 + 2 * k];
    float dx = omS[lp * 33 + 2 * k + 1];
    float m = 1.f / (1.f + expf(-omS[lp * 33 + 18 + k]));

    float ys = (float)(py + k / 3 - 1) + dy;
    float xs = (float)(px + k % 3 - 1) + dx;
    float y0f = floorf(ys), x0f = floorf(xs);
    float wy = ys - y0f, wx = xs - x0f;
    int y0 = (int)y0f, x0 = (int)x0f;
    int y1 = y0 + 1, x1 = x0 + 1;

    bool vy0 = (y0 >= 0) & (y0 < Hn);
    bool vy1 = (y1 >= 0) & (y1 < Hn);
    bool vx0 = (x0 >= 0) & (x0 < Wn);
    bool vx1 = (x1 >= 0) & (x1 < Wn);
    int y0c = min(max(y0, 0), Hn - 1), y1c = min(max(y1, 0), Hn - 1);
    int x0c = min(max(x0, 0), Wn - 1), x1c = min(max(x1, 0), Wn - 1);

    int base = bi * HWn;
    float* s = &sampS[lp][k][0];
    ((int*)s)[0] = (base + y0c * Wn + x0c) * Cn;
    ((int*)s)[1] = (base + y0c * Wn + x1c) * Cn;
    ((int*)s)[2] = (base + y1c * Wn + x0c) * Cn;
    ((int*)s)[3] = (base + y1c * Wn + x1c) * Cn;
    s[4] = (vy0 && vx0) ? m * (1.f - wy) * (1.f - wx) : 0.f;
    s[5] = (vy0 && vx1) ? m * (1.f - wy) * wx : 0.f;
    s[6] = (vy1 && vx0) ? m * wy * (1.f - wx) : 0.f;
    s[7] = (vy1 && vx1) ? m * wy * wx : 0.f;
  }
  __syncthreads();

  // ================= phase 2: deformable main GEMM =================
  int mw = wave >> 2;          // 0..1 (32-row half)
  int nw = wave & 3;           // 0..3 (64-col group)

  float bj[4];
#pragma unroll
  for (int j = 0; j < 4; ++j) bj[j] = bias[(nw * 4 + j) * 16 + col];

  floatx4 acc[2][4];
#pragma unroll
  for (int i = 0; i < 2; ++i)
#pragma unroll
    for (int j = 0; j < 4; ++j) acc[i][j] = (floatx4){0.f, 0.f, 0.f, 0.f};

  // two full prefetch register sets (ping-pong by chunk parity)
  half8 g00[2], g01[2], g10[2], g11[2];
  half8 bst[2][4];
  int4 ofsS[2];
  float4 wvS[2];

  // prologue: tap0 from LDS; issue chunk-0 loads into set 0
  ofsS[0] = *(const int4*)&sampS[ar][0][0];
  wvS[0] = *(const float4*)&sampS[ar][0][4];
  g00[0] = *(const half8*)(xh + (size_t)ofsS[0].x + aci);
  g01[0] = *(const half8*)(xh + (size_t)ofsS[0].y + aci);
  g10[0] = *(const half8*)(xh + (size_t)ofsS[0].z + aci);
  g11[0] = *(const half8*)(xh + (size_t)ofsS[0].w + aci);
#pragma unroll
  for (int q = 0; q < 4; ++q)
    bst[0][q] = *(const half8*)(wtp + (size_t)(q * 512 + tid) * 8);

#pragma unroll
  for (int c = 0; c < 36; ++c) {
    int buf = c & 1;
    int t = c >> 2;

    // refresh samp slot for tap t+1 (first address-use at c=4t+3 issue)
    if ((c & 3) == 0 && t + 1 <= 8) {
      int tnl = t + 1;
      ofsS[tnl & 1] = *(const int4*)&sampS[ar][tnl][0];
      wvS[tnl & 1] = *(const float4*)&sampS[ar][tnl][4];
    }

    // issue chunk c+1 loads FIRST into set[!buf] (set[buf] unconsumed yet;
    // its vmcnt wait below is per-register, newer loads stay outstanding)
    if (c < 35) {
      int cn = c + 1;
      int tn = cn >> 2;
      int cin = (cn & 3) * 64;
      int4 ofs = ofsS[tn & 1];
      int ci = cin + aci;
      g00[!buf] = *(const half8*)(xh + (size_t)ofs.x + ci);
      g01[!buf] = *(const half8*)(xh + (size_t)ofs.y + ci);
      g10[!buf] = *(const half8*)(xh + (size_t)ofs.z + ci);
      g11[!buf] = *(const half8*)(xh + (size_t)ofs.w + ci);
      const _Float16* wsrc = wtp + (size_t)cn * 16384;
#pragma unroll
      for (int q = 0; q < 4; ++q)
        bst[!buf][q] = *(const half8*)(wsrc + (size_t)(q * 512 + tid) * 8);
    }

    // stage chunk c from set[buf]
    {
      float4 wv = wvS[t & 1];
      _Float16 h00 = (_Float16)wv.x, h01 = (_Float16)wv.y;
      _Float16 h10 = (_Float16)wv.z, h11 = (_Float16)wv.w;
      half8 r;
#pragma unroll
      for (int e = 0; e < 8; ++e)
        r[e] = g00[buf][e] * h00 + g01[buf][e] * h01 + g10[buf][e] * h10 + g11[buf][e] * h11;
      *(half8*)&As[buf][ar][aci] = r;
    }
#pragma unroll
    for (int q = 0; q < 4; ++q)
      *(half8*)&Bs[buf][(q * 512 + tid) * 8] = bst[buf][q];

    __builtin_amdgcn_s_waitcnt(LGKM0);   // LDS visible; vmem stays outstanding
    __builtin_amdgcn_s_barrier();

    half8 af[2][2];
#pragma unroll
    for (int kq = 0; kq < 2; ++kq)
#pragma unroll
      for (int i = 0; i < 2; ++i)
        af[kq][i] = *(const half8*)&As[buf][mw * 32 + i * 16 + col][kq * 32 + quad * 8];

    half8 bf[2][4];
#pragma unroll
    for (int kq = 0; kq < 2; ++kq)
#pragma unroll
      for (int j = 0; j < 4; ++j)
        bf[kq][j] = *(const half8*)&Bs[buf][((nw * 4 + j) * 2 + kq) * 512 + lane * 8];

#pragma unroll
    for (int kq = 0; kq < 2; ++kq)
#pragma unroll
      for (int i = 0; i < 2; ++i)
#pragma unroll
        for (int j = 0; j < 4; ++j)
          acc[i][j] = __builtin_amdgcn_mfma_f32_16x16x32_f16(
              af[kq][i], bf[kq][j], acc[i][j], 0, 0, 0);
  }

  // epilogue: bias + relu. Hidden layers: f16 NHWC. Last layer: fp32 NCHW
  // direct to d_out (float4: 4 consecutive p = 4 consecutive x).
#pragma unroll
  for (int i = 0; i < 2; ++i)
#pragma unroll
    for (int j = 0; j < 4; ++j) {
      int n = (nw * 4 + j) * 16 + col;
      if (outf) {
        int pb = p0 + mw * 32 + i * 16 + quad * 4;
        int bi = pb >> 12;
        int pyx = pb & 4095;
        float4 v;
        v.x = fmaxf(acc[i][j][0] + bj[j], 0.f);
        v.y = fmaxf(acc[i][j][1] + bj[j], 0.f);
        v.z = fmaxf(acc[i][j][2] + bj[j], 0.f);
        v.w = fmaxf(acc[i][j][3] + bj[j], 0.f);
        *(float4*)(outf + ((size_t)(bi * On + n)) * HWn + pyx) = v;
      } else {
#pragma unroll
        for (int r = 0; r < 4; ++r) {
          int pp = p0 + mw * 32 + i * 16 + quad * 4 + r;
          float v = fmaxf(acc[i][j][r] + bj[j], 0.f);
          outh[(size_t)pp * On + n] = (_Float16)v;
        }
      }
    }
}

// ---------------------------------------------------------------------------
extern "C" void kernel_launch(void* const* d_in, const int* in_sizes, int n_in,
                              void* d_out, int out_size, void* d_ws, size_t ws_size,
                              hipStream_t stream) {
  (void)in_sizes; (void)n_in; (void)out_size; (void)ws_size;
  const float* x = (const float*)d_in[0];

  _Float16* act0h = (_Float16*)d_ws;                     // Pn*Cn f16
  _Float16* act1h = act0h + (size_t)Pn * Cn;             // Pn*Cn f16
  _Float16* wbop  = act1h + (size_t)Pn * Cn;             // 3*36*2048 f16
  _Float16* wtp   = wbop + (size_t)3 * 36 * 2048;        // 3*256*Kc f16

  k_init<<<4960, 256, 0, stream>>>(
      x, act0h,
      (const float*)d_in[3], (const float*)d_in[7], (const float*)d_in[11],
      (const float*)d_in[1], (const float*)d_in[5], (const float*)d_in[9],
      wtp, wbop);

  _Float16* cur = act0h;
  _Float16* nxt = act1h;
  for (int l = 0; l < 3; ++l) {
    const float* b_off = (const float*)d_in[2 + l * 4];
    const float* b     = (const float*)d_in[4 + l * 4];
    k_layer<<<Pn / 64, 512, 0, stream>>>(
        cur, wbop + (size_t)l * 36 * 2048, b_off,
        wtp + (size_t)l * 256 * Kc, b, nxt,
        (l == 2) ? (float*)d_out : nullptr);
    _Float16* tswap = cur; cur = nxt; nxt = tswap;
  }
}